// Round 23
// baseline (236.839 us; speedup 1.0000x reference)
//
#include <hip/hip_runtime.h>

#define M_ROWS 200000
#define NROWS  64
#define NBLK   3125          // 200000 / 64, exact
#define DIM1   320
#define OUTD   416
#define FSTR   196           // stage row stride (floats); 0 conflicts measured (R12+)
#define LDS_FLOATS (NROWS * FSTR)   // 50176 B static (<64KB)

typedef __attribute__((ext_vector_type(4))) float f32x4;
typedef __attribute__((ext_vector_type(2))) float f32x2;
typedef __attribute__((ext_vector_type(8))) short short8;

static __device__ __forceinline__ float4 ld4(const float* p) {
    return *reinterpret_cast<const float4*>(p);
}
static __device__ __forceinline__ f32x2 ld2(const float* p) {
    return *reinterpret_cast<const f32x2*>(p);
}
static __device__ __forceinline__ f32x2 pkfma(f32x2 a, f32x2 b, f32x2 c) {
    return __builtin_elementwise_fma(a, b, c);   // v_pk_fma_f32
}
static __device__ __forceinline__ unsigned short f2bf(float x) {
    unsigned int u = __float_as_uint(x);
    u = (u + 0x7FFFu + ((u >> 16) & 1u)) >> 16;   // RNE
    return (unsigned short)u;
}

// BISECT kernel: R20 (224us, PASS) + exactly ONE new element — the d@w110
// contraction moves from VALU (R20's F2) to MFMA: 0b-repack w110*INV3 (16 frags),
// per-ks af_d, per-C-row s2 frag-scale, 8 D-MFMAs into acc0 -> T1 stages FINAL
// out0. F3 (e, w101) and F4 (g, w112) stay R20's exact f32 VALU passes; no T2/T3.
// If PASS: R22's bug is in {e/g-MFMA, T2, T3}. If FAIL ~1-3: bug in D-path set.
__global__ __launch_bounds__(512, 4)
void tp_hyb_v23(const float* __restrict__ x1,
                const float* __restrict__ x2,
                const float* __restrict__ w000,
                const float* __restrict__ w011,
                const float* __restrict__ w101,
                const float* __restrict__ w110,
                const float* __restrict__ w112,
                float* __restrict__ out) {
    __shared__ __align__(16) float lds[LDS_FLOATS];
    char* fragb = reinterpret_cast<char*>(lds);

    constexpr float INV3 = 0.57735026918962576f;   // 1/sqrt(3)
    constexpr float INV6 = 0.40824829046386302f;   // 1/sqrt(6)

    const int t   = threadIdx.x;
    const int row = t & 63;
    const int q   = t >> 6;                        // wave id 0..7
    const int wv  = __builtin_amdgcn_readfirstlane(q);
    const long rbase = (long)blockIdx.x * NROWS;

    const float* x1r = x1 + (rbase + row) * DIM1;
    float* frS = lds + row * FSTR;

    // per-row (lane=row) x2 constants
    const float4 xr2 = ld4(x2 + (rbase + row) * 4);
    const float s2  = xr2.x;
    const float s2I = s2 * INV3;
    const float vxI = xr2.y * INV3, vyI = xr2.z * INV3, vzI = xr2.w * INV3;
    const float v6x = xr2.y * INV6, v6y = xr2.z * INV6, v6z = xr2.w * INV6;

    // ---- phase 0a: pack {w000: f=0..31 (nt*4+ks), w011: f=32..47} bf16 B-frags [R20 verbatim] ----
    #pragma unroll
    for (int it = 0; it < 6; ++it) {
        const int slot = it * 512 + t;
        const int f = slot >> 6;
        const int l = slot & 63;
        const float* src; int ldn, g;
        if (f < 32) { src = w000; ldn = 128; g = f; }
        else        { src = w011; ldn = 64;  g = f - 32; }
        const int nt  = g >> 2, ks = g & 3;
        const int k0  = ks * 32 + (l >> 4) * 8;
        const int col = nt * 16 + (l & 15);
        short8 v;
        #pragma unroll
        for (int j = 0; j < 8; ++j)
            v[j] = (short)f2bf(src[(size_t)(k0 + j) * ldn + col]);
        *reinterpret_cast<short8*>(fragb + (size_t)f * 1024 + l * 16) = v;
    }
    __syncthreads();

    // ---- F1 MFMA [R20 verbatim]: wave -> row-tile rt=wv>>1, col-half h=wv&1 ----
    const int rt = wv >> 1, h = wv & 1;
    f32x4 acc0[4], accB1[2];
    #pragma unroll
    for (int i = 0; i < 4; ++i) acc0[i] = (f32x4){0.f, 0.f, 0.f, 0.f};
    #pragma unroll
    for (int i = 0; i < 2; ++i) accB1[i] = (f32x4){0.f, 0.f, 0.f, 0.f};
    const long arow2 = rbase + rt * 16 + (row & 15);
    {
        const float* abase = x1 + arow2 * DIM1 + (row >> 4) * 8;
        #pragma unroll
        for (int ks = 0; ks < 4; ++ks) {
            f32x4 p0 = *reinterpret_cast<const f32x4*>(abase + ks * 32);
            f32x4 p1 = *reinterpret_cast<const f32x4*>(abase + ks * 32 + 4);
            short8 af;
            #pragma unroll
            for (int j = 0; j < 4; ++j) {
                af[j]     = (short)f2bf(p0[j]);
                af[4 + j] = (short)f2bf(p1[j]);
            }
            #pragma unroll
            for (int i = 0; i < 4; ++i) {
                const short8 bf = *reinterpret_cast<const short8*>(
                    fragb + (size_t)((4*h + i) * 4 + ks) * 1024 + row * 16);
                acc0[i] = __builtin_amdgcn_mfma_f32_16x16x32_bf16(af, bf, acc0[i], 0, 0, 0);
            }
            #pragma unroll
            for (int i = 0; i < 2; ++i) {
                const short8 bf = *reinterpret_cast<const short8*>(
                    fragb + (size_t)(32 + (2*h + i) * 4 + ks) * 1024 + row * 16);
                accB1[i] = __builtin_amdgcn_mfma_f32_16x16x32_bf16(af, bf, accB1[i], 0, 0, 0);
            }
        }
    }
    __syncthreads();   // 0a frags consumed

    // ---- phase 0b: repack w110*INV3 -> f=0..15 (nt*2+ks) ----
    {
        const int slot = t;                        // 512 threads, need 1024 slots -> 2 iters
        #pragma unroll
        for (int it = 0; it < 2; ++it) {
            const int s2_ = it * 512 + slot;       // 0..1023 = 16 frags x 64 lanes
            const int f = s2_ >> 6;
            const int l = s2_ & 63;
            const int nt  = f >> 1, ks = f & 1;
            const int k0  = ks * 32 + (l >> 4) * 8;
            const int col = nt * 16 + (l & 15);
            short8 v;
            #pragma unroll
            for (int j = 0; j < 8; ++j)
                v[j] = (short)f2bf(w110[(size_t)(k0 + j) * 128 + col] * INV3);
            *reinterpret_cast<short8*>(fragb + (size_t)f * 1024 + l * 16) = v;
        }
    }

    // per-ks stage-2 A-frags for d: u = ks*32 + (row>>4)*8 + j
    short8 af_d[2];
    {
        const float4 xa = ld4(x2 + arow2 * 4);     // A-row's v2
        #pragma unroll
        for (int ks = 0; ks < 2; ++ks) {
            const int u0 = ks * 32 + ((row >> 4) * 8);
            const float* vb = x1 + arow2 * DIM1 + 128 + u0 * 3;
            float qf[24];
            #pragma unroll
            for (int c = 0; c < 6; ++c) {
                float4 v = ld4(vb + 4 * c);
                qf[4*c+0]=v.x; qf[4*c+1]=v.y; qf[4*c+2]=v.z; qf[4*c+3]=v.w;
            }
            #pragma unroll
            for (int j = 0; j < 8; ++j)
                af_d[ks][j] = (short)f2bf(qf[3*j]*xa.y + qf[3*j+1]*xa.z + qf[3*j+2]*xa.w);
        }
    }
    // scale acc0 by s2 of this lane's C-rows (C-row = rt*16 + (lane>>4)*4 + r)
    {
        #pragma unroll
        for (int r = 0; r < 4; ++r) {
            const float s2c = x2[(rbase + rt * 16 + (row >> 4) * 4 + r) * 4];
            #pragma unroll
            for (int i = 0; i < 4; ++i) acc0[i][r] *= s2c;
        }
    }
    __syncthreads();   // 0b frags visible

    // ---- D-MFMAs: acc0 += d @ (w110*INV3), 8 MFMAs ----
    #pragma unroll
    for (int ks = 0; ks < 2; ++ks) {
        #pragma unroll
        for (int i = 0; i < 4; ++i) {
            const short8 bf = *reinterpret_cast<const short8*>(
                fragb + (size_t)((4*h + i) * 2 + ks) * 1024 + row * 16);
            acc0[i] = __builtin_amdgcn_mfma_f32_16x16x32_bf16(af_d[ks], bf, acc0[i], 0, 0, 0);
        }
    }
    __syncthreads();   // frag reads done; LDS free

    // ---- T1: stage out0 (FINAL: s2*A + D) cols 0..127 + b cols 128..191 [R20 pattern] ----
    const int crow0 = rt * 16 + (row >> 4) * 4;
    const int c16 = wv * 16, c8w = wv * 8, c4w = wv * 4;
    #pragma unroll
    for (int i = 0; i < 4; ++i) {
        const int col = (4*h + i) * 16 + (row & 15);
        #pragma unroll
        for (int r = 0; r < 4; ++r)
            lds[(crow0 + r) * FSTR + col] = acc0[i][r];
    }
    #pragma unroll
    for (int i = 0; i < 2; ++i) {
        const int col = 128 + (2*h + i) * 16 + (row & 15);
        #pragma unroll
        for (int r = 0; r < 4; ++r)
            lds[(crow0 + r) * FSTR + col] = accB1[i][r];
    }
    __syncthreads();
    // store out0 directly (lane=row, 64 B contiguous); read back b
    f32x2 accB[4];
    {
        const float* srow = lds + row * FSTR;
        float* orow = out + (rbase + row)*OUTD + c16;
        #pragma unroll
        for (int i = 0; i < 4; ++i)
            *reinterpret_cast<float4*>(orow + 4*i) =
                *reinterpret_cast<const float4*>(srow + c16 + 4*i);
        #pragma unroll
        for (int c = 0; c < 4; ++c) accB[c] = ld2(srow + 128 + c8w + 2*c);
    }
    __syncthreads();   // stage reads done before featV overwrite

    // ---- stage featV = [v0 | v1 | v2] [R20 verbatim] ----
    {
        float qf[24];
        #pragma unroll
        for (int c = 0; c < 6; ++c) {
            float4 v = ld4(x1r + 128 + 24*q + 4*c);
            qf[4*c+0]=v.x; qf[4*c+1]=v.y; qf[4*c+2]=v.z; qf[4*c+3]=v.w;
        }
        #pragma unroll
        for (int i = 0; i < 8; ++i) {
            const int u = 8*q + i;
            frS[u]       = qf[3*i+0];
            frS[64 + u]  = qf[3*i+1];
            frS[128 + u] = qf[3*i+2];
        }
    }
    __syncthreads();

    // ---- F3: e pass (VALU, R20 verbatim) -> e[3] (w101, 8 cols); combine with accB ----
    f32x2 e0[4], e1[4], e2[4];
    #pragma unroll
    for (int i = 0; i < 4; ++i) {
        e0[i] = (f32x2){0.f, 0.f}; e1[i] = (f32x2){0.f, 0.f}; e2[i] = (f32x2){0.f, 0.f};
    }
    {
        const float* wb = w101 + c8w;
        #pragma unroll 2
        for (int ut = 0; ut < 8; ++ut) {
            f32x4 a0 = *reinterpret_cast<const f32x4*>(frS + 8*ut);
            f32x4 a1 = *reinterpret_cast<const f32x4*>(frS + 8*ut + 4);
            f32x4 b0 = *reinterpret_cast<const f32x4*>(frS + 64 + 8*ut);
            f32x4 b1 = *reinterpret_cast<const f32x4*>(frS + 64 + 8*ut + 4);
            f32x4 c0 = *reinterpret_cast<const f32x4*>(frS + 128 + 8*ut);
            f32x4 c1 = *reinterpret_cast<const f32x4*>(frS + 128 + 8*ut + 4);
            #pragma unroll
            for (int j = 0; j < 8; ++j) {
                const float fa = (j < 4) ? a0[j] : a1[j-4];
                const float fb = (j < 4) ? b0[j] : b1[j-4];
                const float fc = (j < 4) ? c0[j] : c1[j-4];
                const f32x2 faa = {fa, fa}, fbb = {fb, fb}, fcc = {fc, fc};
                const float* wp = wb + (size_t)(8*ut + j) * 64;
                #pragma unroll
                for (int c = 0; c < 4; ++c) {
                    const f32x2 w = ld2(wp + 2*c);
                    e0[c] = pkfma(w, faa, e0[c]);
                    e1[c] = pkfma(w, fbb, e1[c]);
                    e2[c] = pkfma(w, fcc, e2[c]);
                }
            }
        }
    }
    // out1 epilogue + store [R20 verbatim]
    {
        float vals[24];
        #pragma unroll
        for (int c = 0; c < 8; ++c) {
            const float b   = accB[c >> 1][c & 1];
            const float ev0 = e0[c >> 1][c & 1];
            const float ev1 = e1[c >> 1][c & 1];
            const float ev2 = e2[c >> 1][c & 1];
            vals[3*c+0] = vxI*b + s2I*ev0;
            vals[3*c+1] = vyI*b + s2I*ev1;
            vals[3*c+2] = vzI*b + s2I*ev2;
        }
        float* orow = out + (rbase + row)*OUTD + 128 + wv*24;
        #pragma unroll
        for (int i = 0; i < 6; ++i)
            *reinterpret_cast<float4*>(orow + 4*i) =
                make_float4(vals[4*i], vals[4*i+1], vals[4*i+2], vals[4*i+3]);
    }

    // ---- F4: G pass (VALU, R20 verbatim) -> g[3] (w112, 4 cols); cross epilogue ----
    f32x2 g0[2], g1[2], g2[2];
    #pragma unroll
    for (int i = 0; i < 2; ++i) {
        g0[i] = (f32x2){0.f, 0.f}; g1[i] = (f32x2){0.f, 0.f}; g2[i] = (f32x2){0.f, 0.f};
    }
    {
        const float* wb = w112 + c4w;
        #pragma unroll 2
        for (int ut = 0; ut < 8; ++ut) {
            f32x4 a0 = *reinterpret_cast<const f32x4*>(frS + 8*ut);
            f32x4 a1 = *reinterpret_cast<const f32x4*>(frS + 8*ut + 4);
            f32x4 b0 = *reinterpret_cast<const f32x4*>(frS + 64 + 8*ut);
            f32x4 b1 = *reinterpret_cast<const f32x4*>(frS + 64 + 8*ut + 4);
            f32x4 c0 = *reinterpret_cast<const f32x4*>(frS + 128 + 8*ut);
            f32x4 c1 = *reinterpret_cast<const f32x4*>(frS + 128 + 8*ut + 4);
            #pragma unroll
            for (int j = 0; j < 8; ++j) {
                const float fa = (j < 4) ? a0[j] : a1[j-4];
                const float fb = (j < 4) ? b0[j] : b1[j-4];
                const float fc = (j < 4) ? c0[j] : c1[j-4];
                const f32x2 faa = {fa, fa}, fbb = {fb, fb}, fcc = {fc, fc};
                const float* wp = wb + (size_t)(8*ut + j) * 32;
                #pragma unroll
                for (int c = 0; c < 2; ++c) {
                    const f32x2 w = ld2(wp + 2*c);
                    g0[c] = pkfma(w, faa, g0[c]);
                    g1[c] = pkfma(w, fbb, g1[c]);
                    g2[c] = pkfma(w, fcc, g2[c]);
                }
            }
        }
    }
    // out2 epilogue [R20 verbatim]
    {
        float ov[12];
        #pragma unroll
        for (int wl = 0; wl < 4; ++wl) {
            const float G0 = g0[wl >> 1][wl & 1];
            const float G1 = g1[wl >> 1][wl & 1];
            const float G2 = g2[wl >> 1][wl & 1];
            ov[3*wl+0] = G1*v6z - G2*v6y;
            ov[3*wl+1] = G2*v6x - G0*v6z;
            ov[3*wl+2] = G0*v6y - G1*v6x;
        }
        float* orow = out + (rbase + row)*OUTD + 320 + wv*12;
        #pragma unroll
        for (int i = 0; i < 3; ++i)
            *reinterpret_cast<float4*>(orow + 4*i) =
                make_float4(ov[4*i], ov[4*i+1], ov[4*i+2], ov[4*i+3]);
    }
}

extern "C" void kernel_launch(void* const* d_in, const int* in_sizes, int n_in,
                              void* d_out, int out_size, void* d_ws, size_t ws_size,
                              hipStream_t stream) {
    const float* x1   = (const float*)d_in[0];
    const float* x2   = (const float*)d_in[1];
    const float* w000 = (const float*)d_in[2];
    const float* w011 = (const float*)d_in[3];
    const float* w101 = (const float*)d_in[4];
    const float* w110 = (const float*)d_in[5];
    const float* w112 = (const float*)d_in[6];
    // d_in[7] = w3j111 — folded analytically (cross with v2, scaled 1/sqrt6).
    float* out = (float*)d_out;

    tp_hyb_v23<<<dim3(NBLK), dim3(512), 0, stream>>>(
        x1, x2, w000, w011, w101, w110, w112, out);
}

// Round 25
// 224.535 us; speedup vs baseline: 1.0548x; 1.0548x over previous
//
#include <hip/hip_runtime.h>

#define M_ROWS 200000
#define NROWS  64            // rows per block = lanes per wave
#define NBLK   3125          // 200000 / 64, exact
#define DIM1   320
#define OUTD   416
#define FSTR   196           // stage/featV row stride (floats); 0 conflicts measured (R12+)
#define LDS_FLOATS (NROWS * FSTR)   // 50176 B static (<64KB — R3-R5's >64KB dynamic LDS was corrupt)

typedef __attribute__((ext_vector_type(4))) float f32x4;
typedef __attribute__((ext_vector_type(2))) float f32x2;
typedef __attribute__((ext_vector_type(8))) short short8;

static __device__ __forceinline__ float4 ld4(const float* p) {
    return *reinterpret_cast<const float4*>(p);
}
static __device__ __forceinline__ f32x2 ld2(const float* p) {
    return *reinterpret_cast<const f32x2*>(p);
}
static __device__ __forceinline__ f32x2 pkfma(f32x2 a, f32x2 b, f32x2 c) {
    return __builtin_elementwise_fma(a, b, c);   // v_pk_fma_f32
}
static __device__ __forceinline__ unsigned short f2bf(float x) {
    unsigned int u = __float_as_uint(x);
    u = (u + 0x7FFFu + ((u >> 16) & 1u)) >> 16;   // RNE
    return (unsigned short)u;
}

// === FINAL: R20 verbatim (224.3us, fully validated incl. tripwire). ===
// Hybrid: F1 (x1s@w000 + x1s@w011, 48% of MACs) via bf16 MFMA with static <64KB
// LDS frags; C transposed through LDS back to lane=row registers; F2/F3/F4
// (d/e/g) as packed-f32 VALU passes over one LDS-staged featV; one x1 read.
// Rejected by measurement: D/e/g-MFMA conversion (R23 slower; R22/R24
// nondeterministic — unlocalized race in the 2nd transpose round), bf16 featV
// (R18), coalesced x1s staging (R15), mega-fusion (R14), manual dbuf (R10),
// launch_bounds reg-squeeze (R8), quad-map stores (R7).
__global__ __launch_bounds__(512, 4)
void tp_hyb_v25(const float* __restrict__ x1,
                const float* __restrict__ x2,
                const float* __restrict__ w000,
                const float* __restrict__ w011,
                const float* __restrict__ w101,
                const float* __restrict__ w110,
                const float* __restrict__ w112,
                float* __restrict__ out) {
    __shared__ __align__(16) float lds[LDS_FLOATS];
    char* fragb = reinterpret_cast<char*>(lds);

    constexpr float INV3 = 0.57735026918962576f;   // 1/sqrt(3)
    constexpr float INV6 = 0.40824829046386302f;   // 1/sqrt(6)

    const int t   = threadIdx.x;
    const int row = t & 63;                        // lane = row (64-thread waves)
    const int q   = t >> 6;                        // wave id 0..7
    const int wv  = __builtin_amdgcn_readfirstlane(q);
    const long rbase = (long)blockIdx.x * NROWS;

    const float* x1r = x1 + (rbase + row) * DIM1;
    float* frS = lds + row * FSTR;

    // per-row (lane=row) x2 constants
    const float4 xr2 = ld4(x2 + (rbase + row) * 4);
    const float s2  = xr2.x;
    const float s2I = s2 * INV3;
    const float vxI = xr2.y * INV3, vyI = xr2.z * INV3, vzI = xr2.w * INV3;
    const float v6x = xr2.y * INV6, v6y = xr2.z * INV6, v6z = xr2.w * INV6;

    // ---- phase 0: pack B-frags (bf16, raw scale). f<32: w000 [f=nt*4+ks]; else w011 ----
    #pragma unroll
    for (int it = 0; it < 6; ++it) {
        const int slot = it * 512 + t;             // 0..3071 = 48 frags x 64 lanes
        const int f = slot >> 6;
        const int l = slot & 63;
        const float* src; int ldn, g;
        if (f < 32) { src = w000; ldn = 128; g = f; }
        else        { src = w011; ldn = 64;  g = f - 32; }
        const int nt  = g >> 2, ks = g & 3;
        const int k0  = ks * 32 + (l >> 4) * 8;
        const int col = nt * 16 + (l & 15);
        short8 v;
        #pragma unroll
        for (int j = 0; j < 8; ++j)
            v[j] = (short)f2bf(src[(size_t)(k0 + j) * ldn + col]);
        *reinterpret_cast<short8*>(fragb + (size_t)f * 1024 + l * 16) = v;
    }
    __syncthreads();

    // ---- F1-MFMA: wave -> row-tile rt = wv>>1 (16 rows), col-half h = wv&1 ----
    const int rt = wv >> 1, h = wv & 1;
    f32x4 acc0[4], accB1[2];
    #pragma unroll
    for (int i = 0; i < 4; ++i) acc0[i] = (f32x4){0.f, 0.f, 0.f, 0.f};
    #pragma unroll
    for (int i = 0; i < 2; ++i) accB1[i] = (f32x4){0.f, 0.f, 0.f, 0.f};
    {
        // A-row for this lane: rbase + rt*16 + (lane&15); k-slice (lane>>4)*8
        const float* abase = x1 + (rbase + rt * 16 + (row & 15)) * DIM1 + (row >> 4) * 8;
        #pragma unroll
        for (int ks = 0; ks < 4; ++ks) {
            f32x4 p0 = *reinterpret_cast<const f32x4*>(abase + ks * 32);
            f32x4 p1 = *reinterpret_cast<const f32x4*>(abase + ks * 32 + 4);
            short8 af;
            #pragma unroll
            for (int j = 0; j < 4; ++j) {
                af[j]     = (short)f2bf(p0[j]);
                af[4 + j] = (short)f2bf(p1[j]);
            }
            #pragma unroll
            for (int i = 0; i < 4; ++i) {
                const short8 bf = *reinterpret_cast<const short8*>(
                    fragb + (size_t)((4*h + i) * 4 + ks) * 1024 + row * 16);
                acc0[i] = __builtin_amdgcn_mfma_f32_16x16x32_bf16(af, bf, acc0[i], 0, 0, 0);
            }
            #pragma unroll
            for (int i = 0; i < 2; ++i) {
                const short8 bf = *reinterpret_cast<const short8*>(
                    fragb + (size_t)(32 + (2*h + i) * 4 + ks) * 1024 + row * 16);
                accB1[i] = __builtin_amdgcn_mfma_f32_16x16x32_bf16(af, bf, accB1[i], 0, 0, 0);
            }
        }
    }
    __syncthreads();   // frags fully consumed before stage overwrite

    // ---- C transpose -> LDS stage[row][FSTR]: out0 cols 0..127, out1-b cols 128..191 ----
    // D layout: col = lane&15, row = (lane>>4)*4 + r (m89)
    {
        #pragma unroll
        for (int i = 0; i < 4; ++i) {
            const int colb = (4*h + i) * 16 + (row & 15);
            #pragma unroll
            for (int r = 0; r < 4; ++r)
                lds[(rt * 16 + (row >> 4) * 4 + r) * FSTR + colb] = acc0[i][r];
        }
        #pragma unroll
        for (int i = 0; i < 2; ++i) {
            const int colb = 128 + (2*h + i) * 16 + (row & 15);
            #pragma unroll
            for (int r = 0; r < 4; ++r)
                lds[(rt * 16 + (row >> 4) * 4 + r) * FSTR + colb] = accB1[i][r];
        }
    }
    __syncthreads();

    // ---- read back lane=row into accumulator layout ----
    const int c16 = wv * 16, c8w = wv * 8, c4w = wv * 4;
    f32x2 accA[8], accB[4];
    #pragma unroll
    for (int c = 0; c < 8; ++c) accA[c] = ld2(lds + row * FSTR + c16 + 2*c);
    #pragma unroll
    for (int c = 0; c < 4; ++c) accB[c] = ld2(lds + row * FSTR + 128 + c8w + 2*c);
    {
        const f32x2 s2v = {s2, s2};
        #pragma unroll
        for (int i = 0; i < 8; ++i) accA[i] *= s2v;   // out0 = s2*A + (d @ w110)
    }
    __syncthreads();   // stage reads done before featV overwrite

    // ---- stage featV = [v0 | v1 | v2] ----
    {
        float qf[24];
        #pragma unroll
        for (int c = 0; c < 6; ++c) {
            float4 v = ld4(x1r + 128 + 24*q + 4*c);
            qf[4*c+0]=v.x; qf[4*c+1]=v.y; qf[4*c+2]=v.z; qf[4*c+3]=v.w;
        }
        #pragma unroll
        for (int i = 0; i < 8; ++i) {
            const int u = 8*q + i;
            frS[u]       = qf[3*i+0];
            frS[64 + u]  = qf[3*i+1];
            frS[128 + u] = qf[3*i+2];
        }
    }
    __syncthreads();

    // ---- F2: d pass -> accA += (x1v.v2)*INV3 @ w110 ----
    {
        const float* wa = w110 + c16;
        const f32x2 vx2 = {vxI, vxI}, vy2 = {vyI, vyI}, vz2 = {vzI, vzI};
        #pragma unroll 2
        for (int ut = 0; ut < 8; ++ut) {
            f32x2 dp[4];
            #pragma unroll
            for (int p = 0; p < 4; ++p) {
                f32x2 ap = ld2(frS + 8*ut + 2*p);
                f32x2 bp = ld2(frS + 64 + 8*ut + 2*p);
                f32x2 cp = ld2(frS + 128 + 8*ut + 2*p);
                dp[p] = pkfma(cp, vz2, pkfma(bp, vy2, ap * vx2));
            }
            #pragma unroll
            for (int j = 0; j < 8; ++j) {
                const float fd = dp[j >> 1][j & 1];
                const f32x2 fdd = {fd, fd};
                const float* wp = wa + (size_t)(8*ut + j) * 128;
                #pragma unroll
                for (int c = 0; c < 8; ++c)
                    accA[c] = pkfma(ld2(wp + 2*c), fdd, accA[c]);
            }
        }
    }
    // store out0: 64 B contiguous per lane
    {
        float* orow = out + (rbase + row)*OUTD + c16;
        #pragma unroll
        for (int i = 0; i < 4; ++i)
            *reinterpret_cast<float4*>(orow + 4*i) =
                make_float4(accA[2*i][0], accA[2*i][1], accA[2*i+1][0], accA[2*i+1][1]);
    }

    // ---- F3: e pass -> e[3] (w101); combine with accB ----
    f32x2 e0[4], e1[4], e2[4];
    #pragma unroll
    for (int i = 0; i < 4; ++i) {
        e0[i] = (f32x2){0.f, 0.f}; e1[i] = (f32x2){0.f, 0.f}; e2[i] = (f32x2){0.f, 0.f};
    }
    {
        const float* wb = w101 + c8w;
        #pragma unroll 2
        for (int ut = 0; ut < 8; ++ut) {
            f32x4 a0 = *reinterpret_cast<const f32x4*>(frS + 8*ut);
            f32x4 a1 = *reinterpret_cast<const f32x4*>(frS + 8*ut + 4);
            f32x4 b0 = *reinterpret_cast<const f32x4*>(frS + 64 + 8*ut);
            f32x4 b1 = *reinterpret_cast<const f32x4*>(frS + 64 + 8*ut + 4);
            f32x4 c0 = *reinterpret_cast<const f32x4*>(frS + 128 + 8*ut);
            f32x4 c1 = *reinterpret_cast<const f32x4*>(frS + 128 + 8*ut + 4);
            #pragma unroll
            for (int j = 0; j < 8; ++j) {
                const float fa = (j < 4) ? a0[j] : a1[j-4];
                const float fb = (j < 4) ? b0[j] : b1[j-4];
                const float fc = (j < 4) ? c0[j] : c1[j-4];
                const f32x2 faa = {fa, fa}, fbb = {fb, fb}, fcc = {fc, fc};
                const float* wp = wb + (size_t)(8*ut + j) * 64;
                #pragma unroll
                for (int c = 0; c < 4; ++c) {
                    const f32x2 w = ld2(wp + 2*c);
                    e0[c] = pkfma(w, faa, e0[c]);
                    e1[c] = pkfma(w, fbb, e1[c]);
                    e2[c] = pkfma(w, fcc, e2[c]);
                }
            }
        }
    }
    // out1 epilogue + store
    {
        float vals[24];
        #pragma unroll
        for (int c = 0; c < 8; ++c) {
            const float b   = accB[c >> 1][c & 1];
            const float ev0 = e0[c >> 1][c & 1];
            const float ev1 = e1[c >> 1][c & 1];
            const float ev2 = e2[c >> 1][c & 1];
            vals[3*c+0] = vxI*b + s2I*ev0;
            vals[3*c+1] = vyI*b + s2I*ev1;
            vals[3*c+2] = vzI*b + s2I*ev2;
        }
        float* orow = out + (rbase + row)*OUTD + 128 + wv*24;
        #pragma unroll
        for (int i = 0; i < 6; ++i)
            *reinterpret_cast<float4*>(orow + 4*i) =
                make_float4(vals[4*i], vals[4*i+1], vals[4*i+2], vals[4*i+3]);
    }

    // ---- F4: G pass -> g[3] (w112); cross epilogue ----
    f32x2 g0[2], g1[2], g2[2];
    #pragma unroll
    for (int i = 0; i < 2; ++i) {
        g0[i] = (f32x2){0.f, 0.f}; g1[i] = (f32x2){0.f, 0.f}; g2[i] = (f32x2){0.f, 0.f};
    }
    {
        const float* wb = w112 + c4w;
        #pragma unroll 2
        for (int ut = 0; ut < 8; ++ut) {
            f32x4 a0 = *reinterpret_cast<const f32x4*>(frS + 8*ut);
            f32x4 a1 = *reinterpret_cast<const f32x4*>(frS + 8*ut + 4);
            f32x4 b0 = *reinterpret_cast<const f32x4*>(frS + 64 + 8*ut);
            f32x4 b1 = *reinterpret_cast<const f32x4*>(frS + 64 + 8*ut + 4);
            f32x4 c0 = *reinterpret_cast<const f32x4*>(frS + 128 + 8*ut);
            f32x4 c1 = *reinterpret_cast<const f32x4*>(frS + 128 + 8*ut + 4);
            #pragma unroll
            for (int j = 0; j < 8; ++j) {
                const float fa = (j < 4) ? a0[j] : a1[j-4];
                const float fb = (j < 4) ? b0[j] : b1[j-4];
                const float fc = (j < 4) ? c0[j] : c1[j-4];
                const f32x2 faa = {fa, fa}, fbb = {fb, fb}, fcc = {fc, fc};
                const float* wp = wb + (size_t)(8*ut + j) * 32;
                #pragma unroll
                for (int c = 0; c < 2; ++c) {
                    const f32x2 w = ld2(wp + 2*c);
                    g0[c] = pkfma(w, faa, g0[c]);
                    g1[c] = pkfma(w, fbb, g1[c]);
                    g2[c] = pkfma(w, fcc, g2[c]);
                }
            }
        }
    }
    // out2 epilogue: cross(G, v)*INV6
    {
        float ov[12];
        #pragma unroll
        for (int wl = 0; wl < 4; ++wl) {
            const float G0 = g0[wl >> 1][wl & 1];
            const float G1 = g1[wl >> 1][wl & 1];
            const float G2 = g2[wl >> 1][wl & 1];
            ov[3*wl+0] = G1*v6z - G2*v6y;
            ov[3*wl+1] = G2*v6x - G0*v6z;
            ov[3*wl+2] = G0*v6y - G1*v6x;
        }
        float* orow = out + (rbase + row)*OUTD + 320 + wv*12;
        #pragma unroll
        for (int i = 0; i < 3; ++i)
            *reinterpret_cast<float4*>(orow + 4*i) =
                make_float4(ov[4*i], ov[4*i+1], ov[4*i+2], ov[4*i+3]);
    }
}

extern "C" void kernel_launch(void* const* d_in, const int* in_sizes, int n_in,
                              void* d_out, int out_size, void* d_ws, size_t ws_size,
                              hipStream_t stream) {
    const float* x1   = (const float*)d_in[0];
    const float* x2   = (const float*)d_in[1];
    const float* w000 = (const float*)d_in[2];
    const float* w011 = (const float*)d_in[3];
    const float* w101 = (const float*)d_in[4];
    const float* w110 = (const float*)d_in[5];
    const float* w112 = (const float*)d_in[6];
    // d_in[7] = w3j111 — folded analytically (cross with v2, scaled 1/sqrt6).
    float* out = (float*)d_out;

    tp_hyb_v25<<<dim3(NBLK), dim3(512), 0, stream>>>(
        x1, x2, w000, w011, w101, w110, w112, out);
}